// Round 1
// baseline (737.942 us; speedup 1.0000x reference)
//
#include <hip/hip_runtime.h>

// Problem constants (match reference)
#define BGRAPH 64
#define NNODE  128
#define EMB    16
#define OUTF   64
#define EREAL  65536
#define TOTAL  (BGRAPH * NNODE * NNODE)   // 1048576 pairs

// Kernel 1: out_val[p][o] = sum_k gm_val[p][k] * W[o][k]
// 16 threads per row (each computes 4 contiguous outputs), 16 rows per 256-thread block.
__global__ __launch_bounds__(256) void gemm_rows_kernel(
    const float* __restrict__ gm_val,
    const float* __restrict__ W,
    float* __restrict__ out_val)
{
    __shared__ float Ws[OUTF * EMB];   // 1024 floats = 4 KB
    int tid = threadIdx.x;
    // cooperative load of W: 256 threads x float4 = 1024 floats
    ((float4*)Ws)[tid] = ((const float4*)W)[tid];
    __syncthreads();

    int row = blockIdx.x * 16 + (tid >> 4);   // pair index p
    int oq  = tid & 15;                        // output quad: outputs [4*oq, 4*oq+3]

    const float4* v4 = (const float4*)(gm_val + (size_t)row * EMB);
    float4 a = v4[0], b = v4[1], c = v4[2], d = v4[3];
    float v[16] = {a.x,a.y,a.z,a.w, b.x,b.y,b.z,b.w,
                   c.x,c.y,c.z,c.w, d.x,d.y,d.z,d.w};

    float4 o;
    float* op = &o.x;
    #pragma unroll
    for (int j = 0; j < 4; ++j) {
        int oo = oq * 4 + j;
        float s = 0.0f;
        #pragma unroll
        for (int k = 0; k < EMB; ++k)
            s += v[k] * Ws[oo * EMB + k];   // same addr across wave -> LDS broadcast
        op[j] = s;
    }
    *((float4*)(out_val + (size_t)row * OUTF + oq * 4)) = o;
}

// Kernel 2: atomic scatter-add of real-edge attrs.
// One thread per (edge, channel); a 64-lane wave covers one edge's 64 channels.
__global__ __launch_bounds__(256) void scatter_edges_kernel(
    const int* __restrict__ edge_index,   // [2, EREAL] flat: src then dst
    const float* __restrict__ edge_attr,  // [EREAL, OUTF]
    float* __restrict__ out_val)
{
    int idx = blockIdx.x * 256 + threadIdx.x;
    int e = idx >> 6;
    int o = idx & 63;
    int src = edge_index[e];
    int dst = edge_index[EREAL + e];
    // flat pair id: src*128 + (dst % 128)
    int fid = src * NNODE + (dst & (NNODE - 1));
    atomicAdd(out_val + (size_t)fid * OUTF + o, edge_attr[(size_t)e * OUTF + o]);
}

// Kernel 3: closed-form coalesced index output (as float32).
__global__ __launch_bounds__(256) void write_idx_kernel(float* __restrict__ out_idx)
{
    int p = blockIdx.x * 256 + threadIdx.x;   // p in [0, TOTAL)
    int g   = p >> 14;          // / (N*N)
    int rem = p & 16383;        // % (N*N)
    out_idx[p]         = (float)(g * NNODE + (rem >> 7));   // src row
    out_idx[TOTAL + p] = (float)(g * NNODE + (rem & 127));  // dst row
}

extern "C" void kernel_launch(void* const* d_in, const int* in_sizes, int n_in,
                              void* d_out, int out_size, void* d_ws, size_t ws_size,
                              hipStream_t stream)
{
    // inputs (setup_inputs order): batch, edge_index, edge_attr, gm_index, gm_val, W
    const int*   edge_index = (const int*)d_in[1];
    const float* edge_attr  = (const float*)d_in[2];
    const float* gm_val     = (const float*)d_in[4];
    const float* W          = (const float*)d_in[5];

    float* out      = (float*)d_out;
    float* out_idx  = out;                    // first 2*TOTAL elements
    float* out_val  = out + (size_t)2 * TOTAL; // then TOTAL*OUTF elements

    // 1) dense gm projection (overwrites poison)
    gemm_rows_kernel<<<TOTAL / 16, 256, 0, stream>>>(gm_val, W, out_val);
    // 2) scatter-add real edges (after values are initialized; same stream serializes)
    scatter_edges_kernel<<<(EREAL * OUTF) / 256, 256, 0, stream>>>(edge_index, edge_attr, out_val);
    // 3) index output
    write_idx_kernel<<<TOTAL / 256, 256, 0, stream>>>(out_idx);
}

// Round 2
// 479.234 us; speedup vs baseline: 1.5398x; 1.5398x over previous
//
#include <hip/hip_runtime.h>

// Problem constants (match reference)
#define BGRAPH 64
#define NNODE  128
#define EMB    16
#define OUTF   64
#define EREAL  65536
#define TOTAL  (BGRAPH * NNODE * NNODE)   // 1048576 pairs

#define GEMM_BLOCKS 4096   // 16 rows per block-iteration -> 16 grid-stride iters

// Kernel 1: out_val[p][o] = sum_k gm_val[p][k] * W[o][k]
// 16 threads per row, each computes 4 contiguous outputs. W slice held in
// REGISTERS (64 floats/thread) -- no LDS, no bank conflicts. Grid-stride
// amortizes the weight load over 16 rows/thread.
__global__ __launch_bounds__(256) void gemm_rows_kernel(
    const float* __restrict__ gm_val,
    const float* __restrict__ W,
    float* __restrict__ out_val)
{
    int tid = threadIdx.x;
    int oq  = tid & 15;                  // output quad: outputs [4*oq, 4*oq+3]

    // Load my 4 rows of W (contiguous 64 floats = 16 float4) into registers.
    // W is 4 KB total -> L2-resident broadcast across all blocks.
    float w[4][16];
    const float4* W4 = (const float4*)W + oq * 16;
    #pragma unroll
    for (int j = 0; j < 4; ++j) {
        #pragma unroll
        for (int q = 0; q < 4; ++q) {
            float4 t = W4[j * 4 + q];
            w[j][q * 4 + 0] = t.x;
            w[j][q * 4 + 1] = t.y;
            w[j][q * 4 + 2] = t.z;
            w[j][q * 4 + 3] = t.w;
        }
    }

    int row0   = blockIdx.x * 16 + (tid >> 4);
    int stride = GEMM_BLOCKS * 16;

    for (int row = row0; row < TOTAL; row += stride) {
        const float4* v4 = (const float4*)(gm_val + (size_t)row * EMB);
        float4 a = v4[0], b = v4[1], c = v4[2], d = v4[3];
        float v[16] = {a.x,a.y,a.z,a.w, b.x,b.y,b.z,b.w,
                       c.x,c.y,c.z,c.w, d.x,d.y,d.z,d.w};

        float4 o;
        float* op = &o.x;
        #pragma unroll
        for (int j = 0; j < 4; ++j) {
            float s = 0.0f;
            #pragma unroll
            for (int k = 0; k < EMB; ++k)
                s += v[k] * w[j][k];
            op[j] = s;
        }
        *((float4*)(out_val + (size_t)row * OUTF + oq * 4)) = o;
    }
}

// Kernel 2: atomic scatter-add of real-edge attrs.
// One thread per (edge, channel); a 64-lane wave covers one edge's 64
// contiguous channels (one 256 B segment -> coalesced atomics).
__global__ __launch_bounds__(256) void scatter_edges_kernel(
    const int* __restrict__ edge_index,   // [2, EREAL] flat: src then dst
    const float* __restrict__ edge_attr,  // [EREAL, OUTF]
    float* __restrict__ out_val)
{
    int idx = blockIdx.x * 256 + threadIdx.x;
    int e = idx >> 6;
    int o = idx & 63;
    int src = edge_index[e];
    int dst = edge_index[EREAL + e];
    int fid = src * NNODE + (dst & (NNODE - 1));   // src*128 + dst%128
    atomicAdd(out_val + (size_t)fid * OUTF + o, edge_attr[(size_t)e * OUTF + o]);
}

// Kernel 3: closed-form coalesced index output (as float32).
__global__ __launch_bounds__(256) void write_idx_kernel(float* __restrict__ out_idx)
{
    int p = blockIdx.x * 256 + threadIdx.x;   // p in [0, TOTAL)
    int g   = p >> 14;          // / (N*N)
    int rem = p & 16383;        // % (N*N)
    out_idx[p]         = (float)(g * NNODE + (rem >> 7));   // src row
    out_idx[TOTAL + p] = (float)(g * NNODE + (rem & 127));  // dst row
}

extern "C" void kernel_launch(void* const* d_in, const int* in_sizes, int n_in,
                              void* d_out, int out_size, void* d_ws, size_t ws_size,
                              hipStream_t stream)
{
    // inputs (setup_inputs order): batch, edge_index, edge_attr, gm_index, gm_val, W
    const int*   edge_index = (const int*)d_in[1];
    const float* edge_attr  = (const float*)d_in[2];
    const float* gm_val     = (const float*)d_in[4];
    const float* W          = (const float*)d_in[5];

    float* out      = (float*)d_out;
    float* out_idx  = out;                     // first 2*TOTAL elements
    float* out_val  = out + (size_t)2 * TOTAL; // then TOTAL*OUTF elements

    // 1) dense gm projection (overwrites poison)
    gemm_rows_kernel<<<GEMM_BLOCKS, 256, 0, stream>>>(gm_val, W, out_val);
    // 2) scatter-add real edges (same stream serializes after init)
    scatter_edges_kernel<<<(EREAL * OUTF) / 256, 256, 0, stream>>>(edge_index, edge_attr, out_val);
    // 3) index output
    write_idx_kernel<<<TOTAL / 256, 256, 0, stream>>>(out_idx);
}